// Round 3
// baseline (234.004 us; speedup 1.0000x reference)
//
#include <hip/hip_runtime.h>
#include <math.h>

#define DM 2048
#define NEXP 64
#define NTOK 16384
#define BT 32                 // tokens per block (2 M-tiles of 16)
#define NW 8                  // waves per block
#define KSL (DM / NW)         // 256-wide K slice per wave
#define NKS (KSL / 32)        // 8 k-steps of 32
#define NBLK (NTOK / BT)      // 512 blocks
#define WELEMS (NEXP * DM)    // 131072
#define PNE 68                // padded expert dim in LDS (break 4-way conflict)

typedef __attribute__((ext_vector_type(8))) short short8;
typedef __attribute__((ext_vector_type(4))) float f32x4;

// Split fp32 into three bf16 limbs (RNE each level); hi+mid+lo exact to ~2^-25 rel.
__device__ __forceinline__ void split3(float f, unsigned short& h,
                                       unsigned short& m, unsigned short& l) {
  unsigned u = __float_as_uint(f);
  unsigned rh = (u + 0x7FFFu + ((u >> 16) & 1u)) >> 16;
  h = (unsigned short)rh;
  float f1 = f - __uint_as_float(rh << 16);
  unsigned u1 = __float_as_uint(f1);
  unsigned rm = (u1 + 0x7FFFu + ((u1 >> 16) & 1u)) >> 16;
  m = (unsigned short)rm;
  float f2 = f1 - __uint_as_float(rm << 16);
  unsigned u2 = __float_as_uint(f2);
  l = (unsigned short)((u2 + 0x7FFFu + ((u2 >> 16) & 1u)) >> 16);
}

__global__ void convw_kernel(const float* __restrict__ W,
                             unsigned short* __restrict__ whi,
                             unsigned short* __restrict__ wmid,
                             unsigned short* __restrict__ wlo) {
  int i = blockIdx.x * 256 + threadIdx.x;
  unsigned short h, m, l;
  split3(W[i], h, m, l);
  whi[i] = h; wmid[i] = m; wlo[i] = l;
}

// Fast path: software-pipelined bf16x3 MFMA GEMM + fused top-2 softmax.
// Loop-carried prefetch: A (HBM) and B hi/mid (L2) for kstep+1 load during
// kstep — cross-iteration live ranges the scheduler cannot re-serialize.
__global__ __launch_bounds__(512, 2)
void router_fast(const float* __restrict__ x, const float* __restrict__ bias,
                 const unsigned short* __restrict__ whi,
                 const unsigned short* __restrict__ wmid,
                 const unsigned short* __restrict__ wlo,
                 float* __restrict__ out) {
  const int lane = threadIdx.x & 63;
  const int wv = threadIdx.x >> 6;
  const int col = lane & 15;
  const int quad = lane >> 4;
  const int tok0 = blockIdx.x * BT;
  const int kbase = wv * KSL + quad * 8;

  __shared__ float part[NW][BT][PNE]; // 69.6 KB

  const float* xa0 = x + (size_t)(tok0 + col) * DM + kbase;
  const float* xa1 = xa0 + 16 * DM;
  const size_t wrow = (size_t)col * DM + kbase; // + nt*16*DM + ko

  f32x4 acc[2][4];
#pragma unroll
  for (int ms = 0; ms < 2; ++ms)
#pragma unroll
    for (int nt = 0; nt < 4; ++nt) acc[ms][nt] = (f32x4){0.f, 0.f, 0.f, 0.f};

  // ---- pipeline prologue: loads for ks=0 ----
  f32x4 an[2][2];
  short8 bhn[4], bmn[4];
  an[0][0] = *(const f32x4*)(xa0);
  an[0][1] = *(const f32x4*)(xa0 + 4);
  an[1][0] = *(const f32x4*)(xa1);
  an[1][1] = *(const f32x4*)(xa1 + 4);
#pragma unroll
  for (int nt = 0; nt < 4; ++nt) {
    bhn[nt] = *(const short8*)(whi + wrow + (size_t)nt * 16 * DM);
    bmn[nt] = *(const short8*)(wmid + wrow + (size_t)nt * 16 * DM);
  }

#pragma unroll 2
  for (int ks = 0; ks < NKS; ++ks) {
    const int ko = ks * 32;
    // rotate carried -> current
    f32x4 ac[2][2];
    ac[0][0] = an[0][0]; ac[0][1] = an[0][1];
    ac[1][0] = an[1][0]; ac[1][1] = an[1][1];
    short8 bh[4], bm[4];
#pragma unroll
    for (int nt = 0; nt < 4; ++nt) { bh[nt] = bhn[nt]; bm[nt] = bmn[nt]; }

    // issue next-iteration loads (loop-carried)
    if (ks + 1 < NKS) {
      const int kn = ko + 32;
      an[0][0] = *(const f32x4*)(xa0 + kn);
      an[0][1] = *(const f32x4*)(xa0 + kn + 4);
      an[1][0] = *(const f32x4*)(xa1 + kn);
      an[1][1] = *(const f32x4*)(xa1 + kn + 4);
#pragma unroll
      for (int nt = 0; nt < 4; ++nt) {
        bhn[nt] = *(const short8*)(whi + wrow + (size_t)nt * 16 * DM + kn);
        bmn[nt] = *(const short8*)(wmid + wrow + (size_t)nt * 16 * DM + kn);
      }
    }

    // current-iteration lo limbs (L2 latency covered by split VALU below)
    short8 bl[4];
#pragma unroll
    for (int nt = 0; nt < 4; ++nt)
      bl[nt] = *(const short8*)(wlo + wrow + (size_t)nt * 16 * DM + ko);

    // ---- split A into 3 bf16 limbs ----
    short8 ah[2], am2[2], al2[2];
#pragma unroll
    for (int ms = 0; ms < 2; ++ms) {
      float av[8] = {ac[ms][0].x, ac[ms][0].y, ac[ms][0].z, ac[ms][0].w,
                     ac[ms][1].x, ac[ms][1].y, ac[ms][1].z, ac[ms][1].w};
#pragma unroll
      for (int j = 0; j < 8; ++j) {
        unsigned short h, m, l;
        split3(av[j], h, m, l);
        ah[ms][j] = (short)h; am2[ms][j] = (short)m; al2[ms][j] = (short)l;
      }
    }

    // ---- 6-product MFMA accumulate ----
#pragma unroll
    for (int nt = 0; nt < 4; ++nt) {
#pragma unroll
      for (int ms = 0; ms < 2; ++ms) {
        f32x4 c = acc[ms][nt];
        c = __builtin_amdgcn_mfma_f32_16x16x32_bf16(ah[ms], bh[nt], c, 0, 0, 0);
        c = __builtin_amdgcn_mfma_f32_16x16x32_bf16(ah[ms], bm[nt], c, 0, 0, 0);
        c = __builtin_amdgcn_mfma_f32_16x16x32_bf16(am2[ms], bh[nt], c, 0, 0, 0);
        c = __builtin_amdgcn_mfma_f32_16x16x32_bf16(ah[ms], bl[nt], c, 0, 0, 0);
        c = __builtin_amdgcn_mfma_f32_16x16x32_bf16(al2[ms], bh[nt], c, 0, 0, 0);
        c = __builtin_amdgcn_mfma_f32_16x16x32_bf16(am2[ms], bm[nt], c, 0, 0, 0);
        acc[ms][nt] = c;
      }
    }
  }

  // ---- dump partial logits to LDS: C/D row=quad*4+r, col=lane&15 ----
#pragma unroll
  for (int ms = 0; ms < 2; ++ms)
#pragma unroll
    for (int nt = 0; nt < 4; ++nt)
#pragma unroll
      for (int r = 0; r < 4; ++r)
        part[wv][ms * 16 + quad * 4 + r][nt * 16 + col] = acc[ms][nt][r];
  __syncthreads();

  // ---- reduce K-partials + bias, butterfly top-2 (verified) ----
  const float bl_ = bias[lane];
#pragma unroll
  for (int ti = 0; ti < 4; ++ti) {
    const int t = wv * 4 + ti;
    float v1 = bl_;
#pragma unroll
    for (int p = 0; p < NW; ++p) v1 += part[p][t][lane];
    int i1 = lane;
    float v2 = -INFINITY;
    int i2 = NEXP;
#pragma unroll
    for (int off = 32; off > 0; off >>= 1) {
      float ov1 = __shfl_xor(v1, off, 64);
      int   oi1 = __shfl_xor(i1, off, 64);
      float ov2 = __shfl_xor(v2, off, 64);
      int   oi2 = __shfl_xor(i2, off, 64);
      bool afirst = (v1 > ov1) || (v1 == ov1 && i1 < oi1);
      float w1v = afirst ? v1 : ov1;  int w1i = afirst ? i1 : oi1;
      float c1v = afirst ? v2 : ov2;  int c1i = afirst ? i2 : oi2;
      float c2v = afirst ? ov1 : v1;  int c2i = afirst ? oi1 : i1;
      bool sfirst = (c1v > c2v) || (c1v == c2v && c1i < c2i);
      v1 = w1v; i1 = w1i;
      v2 = sfirst ? c1v : c2v;
      i2 = sfirst ? c1i : c2i;
    }
    if (lane == 0) {
      const float ex = expf(v2 - v1);
      const float den = 1.f + ex;
      const int token = tok0 + t;
      *(float2*)(out + 2 * token) = make_float2(1.f / den, ex / den);
      *(float2*)(out + 2 * NTOK + 2 * token) =
          make_float2((float)i1, (float)i2);
    }
  }
}

// Fallback (ws too small): round-2 verified kernel with inline W split.
__global__ __launch_bounds__(512, 2)
void router_fb(const float* __restrict__ x, const float* __restrict__ W,
               const float* __restrict__ bias, float* __restrict__ out) {
  const int lane = threadIdx.x & 63;
  const int wv = threadIdx.x >> 6;
  const int col = lane & 15;
  const int quad = lane >> 4;
  const int tok0 = blockIdx.x * BT;
  const int k0 = wv * KSL;

  __shared__ float part[NW][BT][PNE];

  f32x4 acc[2][4];
#pragma unroll
  for (int ms = 0; ms < 2; ++ms)
#pragma unroll
    for (int nt = 0; nt < 4; ++nt) acc[ms][nt] = (f32x4){0.f, 0.f, 0.f, 0.f};

  for (int ks = 0; ks < NKS; ++ks) {
    const int k = k0 + ks * 32 + quad * 8;
    short8 ah[2], am2[2], al2[2];
#pragma unroll
    for (int ms = 0; ms < 2; ++ms) {
      const f32x4* ap = (const f32x4*)(x + (size_t)(tok0 + ms * 16 + col) * DM + k);
      f32x4 a0 = ap[0], a1 = ap[1];
      float av[8] = {a0.x, a0.y, a0.z, a0.w, a1.x, a1.y, a1.z, a1.w};
#pragma unroll
      for (int j = 0; j < 8; ++j) {
        unsigned short h, m, l;
        split3(av[j], h, m, l);
        ah[ms][j] = (short)h; am2[ms][j] = (short)m; al2[ms][j] = (short)l;
      }
    }
#pragma unroll
    for (int nt = 0; nt < 4; ++nt) {
      short8 bh, bm, bl;
      const f32x4* wp = (const f32x4*)(W + (size_t)(nt * 16 + col) * DM + k);
      f32x4 w0 = wp[0], w1 = wp[1];
      float wvv[8] = {w0.x, w0.y, w0.z, w0.w, w1.x, w1.y, w1.z, w1.w};
#pragma unroll
      for (int j = 0; j < 8; ++j) {
        unsigned short h, m, l;
        split3(wvv[j], h, m, l);
        bh[j] = (short)h; bm[j] = (short)m; bl[j] = (short)l;
      }
#pragma unroll
      for (int ms = 0; ms < 2; ++ms) {
        f32x4 c = acc[ms][nt];
        c = __builtin_amdgcn_mfma_f32_16x16x32_bf16(ah[ms], bh, c, 0, 0, 0);
        c = __builtin_amdgcn_mfma_f32_16x16x32_bf16(ah[ms], bm, c, 0, 0, 0);
        c = __builtin_amdgcn_mfma_f32_16x16x32_bf16(am2[ms], bh, c, 0, 0, 0);
        c = __builtin_amdgcn_mfma_f32_16x16x32_bf16(ah[ms], bl, c, 0, 0, 0);
        c = __builtin_amdgcn_mfma_f32_16x16x32_bf16(al2[ms], bh, c, 0, 0, 0);
        c = __builtin_amdgcn_mfma_f32_16x16x32_bf16(am2[ms], bm, c, 0, 0, 0);
        acc[ms][nt] = c;
      }
    }
  }
#pragma unroll
  for (int ms = 0; ms < 2; ++ms)
#pragma unroll
    for (int nt = 0; nt < 4; ++nt)
#pragma unroll
      for (int r = 0; r < 4; ++r)
        part[wv][ms * 16 + quad * 4 + r][nt * 16 + col] = acc[ms][nt][r];
  __syncthreads();
  const float bl_ = bias[lane];
#pragma unroll
  for (int ti = 0; ti < 4; ++ti) {
    const int t = wv * 4 + ti;
    float v1 = bl_;
#pragma unroll
    for (int p = 0; p < NW; ++p) v1 += part[p][t][lane];
    int i1 = lane;
    float v2 = -INFINITY;
    int i2 = NEXP;
#pragma unroll
    for (int off = 32; off > 0; off >>= 1) {
      float ov1 = __shfl_xor(v1, off, 64);
      int   oi1 = __shfl_xor(i1, off, 64);
      float ov2 = __shfl_xor(v2, off, 64);
      int   oi2 = __shfl_xor(i2, off, 64);
      bool afirst = (v1 > ov1) || (v1 == ov1 && i1 < oi1);
      float w1v = afirst ? v1 : ov1;  int w1i = afirst ? i1 : oi1;
      float c1v = afirst ? v2 : ov2;  int c1i = afirst ? i2 : oi2;
      float c2v = afirst ? ov1 : v1;  int c2i = afirst ? oi1 : i1;
      bool sfirst = (c1v > c2v) || (c1v == c2v && c1i < c2i);
      v1 = w1v; i1 = w1i;
      v2 = sfirst ? c1v : c2v;
      i2 = sfirst ? c1i : c2i;
    }
    if (lane == 0) {
      const float ex = expf(v2 - v1);
      const float den = 1.f + ex;
      const int token = tok0 + t;
      *(float2*)(out + 2 * token) = make_float2(1.f / den, ex / den);
      *(float2*)(out + 2 * NTOK + 2 * token) =
          make_float2((float)i1, (float)i2);
    }
  }
}

extern "C" void kernel_launch(void* const* d_in, const int* in_sizes, int n_in,
                              void* d_out, int out_size, void* d_ws, size_t ws_size,
                              hipStream_t stream) {
  const float* x = (const float*)d_in[0];
  const float* W = (const float*)d_in[1];
  const float* b = (const float*)d_in[2];
  float* out = (float*)d_out;

  const size_t need = 3ull * WELEMS * sizeof(unsigned short); // 768 KB
  if (ws_size >= need) {
    unsigned short* whi = (unsigned short*)d_ws;
    unsigned short* wmid = whi + WELEMS;
    unsigned short* wlo = wmid + WELEMS;
    hipLaunchKernelGGL(convw_kernel, dim3(WELEMS / 256), dim3(256), 0, stream,
                       W, whi, wmid, wlo);
    hipLaunchKernelGGL(router_fast, dim3(NBLK), dim3(512), 0, stream,
                       x, b, whi, wmid, wlo, out);
  } else {
    hipLaunchKernelGGL(router_fb, dim3(NBLK), dim3(512), 0, stream,
                       x, W, b, out);
  }
}

// Round 4
// 217.251 us; speedup vs baseline: 1.0771x; 1.0771x over previous
//
#include <hip/hip_runtime.h>
#include <math.h>

#define DM 2048
#define NEXP 64
#define NTOK 16384
#define NSLICE 8
#define KSL (DM / NSLICE)     // 256 k per block (K-slice)
#define KC 32                 // k per chunk == one MFMA k-step
#define NCH (KSL / KC)        // 8 chunks per block
#define MB 128                // tokens per block (4 waves x 2 M-tiles x 16)
#define NBLK1 ((NTOK / MB) * NSLICE)  // 1024 blocks
#define WFRAG_BYTES (64 * 12 * 1024)  // [kg 64][limb*4+nt 12][64 lanes][16B]
#define PART_BYTES (NSLICE * NTOK * NEXP * 4)

typedef __attribute__((ext_vector_type(8))) short short8;
typedef __attribute__((ext_vector_type(4))) float f32x4;

// Async global->LDS DMA, 16B per lane. LDS dest = uniform base + lane*16.
// No dest VGPRs -> the compiler cannot re-serialize these; queue depth hides
// latency (the m93->m97 mechanism).
__device__ __forceinline__ void async16(void* lds, const void* g) {
  __builtin_amdgcn_global_load_lds(
      (const __attribute__((address_space(1))) unsigned int*)g,
      (__attribute__((address_space(3))) unsigned int*)lds, 16, 0, 0);
}

// Truncating 3-limb bf16 split: f = h+m+l exact to ~2^-24 rel. (Trunc, not
// RNE: 1 bit worse error, ~half the VALU ops; error budget has 10x headroom.)
__device__ __forceinline__ void split3t(float f, unsigned short& h,
                                        unsigned short& m, unsigned short& l) {
  unsigned u = __float_as_uint(f);
  h = (unsigned short)(u >> 16);
  float f1 = f - __uint_as_float(u & 0xFFFF0000u);   // exact
  unsigned u1 = __float_as_uint(f1);
  m = (unsigned short)(u1 >> 16);
  float f2 = f1 - __uint_as_float(u1 & 0xFFFF0000u); // exact
  l = (unsigned short)(__float_as_uint(f2) >> 16);
}

__device__ __forceinline__ void split8(const f32x4& a0, const f32x4& a1,
                                       short8& h, short8& m, short8& l) {
  float v[8] = {a0[0], a0[1], a0[2], a0[3], a1[0], a1[1], a1[2], a1[3]};
#pragma unroll
  for (int j = 0; j < 8; ++j) {
    unsigned short hh, mm, ll;
    split3t(v[j], hh, mm, ll);
    h[j] = (short)hh; m[j] = (short)mm; l[j] = (short)ll;
  }
}

// Pre-split W into MFMA-B-fragment-ordered limb blocks:
// wfrag[((kg*12 + limb*4 + nt)*64 + lane)*8 + j] =
//   limb of W[nt*16 + (lane&15)][kg*32 + (lane>>4)*8 + j]
__global__ void convw_kernel(const float* __restrict__ W,
                             unsigned short* __restrict__ wfrag) {
  const int kg = blockIdx.x;          // 64 global k-steps
  const int lane = threadIdx.x & 63;
  const int nt = threadIdx.x >> 6;    // 4 n-tiles
  const int e = nt * 16 + (lane & 15);
  const int kpos = kg * 32 + (lane >> 4) * 8;
  const f32x4* wp = (const f32x4*)(W + (size_t)e * DM + kpos);
  f32x4 w0 = wp[0], w1 = wp[1];
  short8 h, m, l;
  split8(w0, w1, h, m, l);
  size_t base = ((size_t)(kg * 12 + nt) * 64 + lane) * 8;
  *(short8*)(wfrag + base) = h;
  *(short8*)(wfrag + base + (size_t)4 * 64 * 8) = m;  // limb slots 4..7
  *(short8*)(wfrag + base + (size_t)8 * 64 * 8) = l;  // limb slots 8..11
}

// K1: DMA-staged bf16x3 MFMA GEMM, partial logits to global.
// Block: 4 waves, 128 tokens, K-slice 256 in 8 chunks of 32.
__global__ __launch_bounds__(256, 4)
void router_gemm(const float* __restrict__ x,
                 const unsigned short* __restrict__ wfrag,
                 float* __restrict__ part) {
  const int lane = threadIdx.x & 63;
  const int wv = threadIdx.x >> 6;
  const int col = lane & 15;
  const int quad = lane >> 4;
  const int tg = blockIdx.x & ((NTOK / MB) - 1);
  const int s = blockIdx.x >> 7;      // K-slice index 0..7
  const int tok0 = tg * MB;

  __shared__ __align__(16) float xs[MB][KC];              // 16 KB
  __shared__ __align__(16) unsigned short bs[12][64][8];  // 12 KB

  f32x4 acc[2][4];
#pragma unroll
  for (int mt = 0; mt < 2; ++mt)
#pragma unroll
    for (int nt = 0; nt < 4; ++nt) acc[mt][nt] = (f32x4){0.f, 0.f, 0.f, 0.f};

  for (int c = 0; c < NCH; ++c) {
    const int kc = s * KSL + c * KC;  // absolute k of this chunk
    const int kg = s * NCH + c;       // global k-step index

    // ---- x tile DMA: wave stages its own 32 token-rows, 4 insts x 1KB.
    // 16B-unit XOR swizzle by (row&7) so A-frag ds_read_b128 hits the
    // conflict floor.
#pragma unroll
    for (int i = 0; i < 4; ++i) {
      const int r = wv * 32 + i * 8;
      const int tr = r + (lane >> 3);
      const int unit = (lane & 7) ^ ((lane >> 3) & 7);
      async16(&xs[r][0],
              x + (size_t)(tok0 + tr) * DM + kc + unit * 4);
    }
    // ---- B fragment DMA: 12 x 1KB blocks, 3 insts per wave, already in
    // frag-lane order (conflict-free ds_read_b128).
#pragma unroll
    for (int q = 0; q < 3; ++q) {
      const int m = wv * 3 + q;
      async16(&bs[m][0][0],
              wfrag + ((size_t)kg * 12 + m) * 512 + (size_t)lane * 8);
    }
    __syncthreads();  // drains vmcnt (DMA complete), publishes LDS

    // ---- A fragments: un-swizzled read + limb split ----
    short8 ah[2], am[2], al[2];
#pragma unroll
    for (int mt = 0; mt < 2; ++mt) {
      const int row = wv * 32 + mt * 16 + col;
      const int u0 = (quad * 2) ^ (row & 7);
      const int u1 = (quad * 2 + 1) ^ (row & 7);
      f32x4 a0 = *(const f32x4*)&xs[row][u0 * 4];
      f32x4 a1 = *(const f32x4*)&xs[row][u1 * 4];
      split8(a0, a1, ah[mt], am[mt], al[mt]);
    }

    // ---- B fragments + 6-product MFMA ----
#pragma unroll
    for (int nt = 0; nt < 4; ++nt) {
      short8 bh = *(const short8*)&bs[nt][lane][0];
      short8 bm = *(const short8*)&bs[4 + nt][lane][0];
      short8 bl = *(const short8*)&bs[8 + nt][lane][0];
#pragma unroll
      for (int mt = 0; mt < 2; ++mt) {
        f32x4 cc = acc[mt][nt];
        cc = __builtin_amdgcn_mfma_f32_16x16x32_bf16(ah[mt], bh, cc, 0, 0, 0);
        cc = __builtin_amdgcn_mfma_f32_16x16x32_bf16(ah[mt], bm, cc, 0, 0, 0);
        cc = __builtin_amdgcn_mfma_f32_16x16x32_bf16(am[mt], bh, cc, 0, 0, 0);
        cc = __builtin_amdgcn_mfma_f32_16x16x32_bf16(ah[mt], bl, cc, 0, 0, 0);
        cc = __builtin_amdgcn_mfma_f32_16x16x32_bf16(al[mt], bh, cc, 0, 0, 0);
        cc = __builtin_amdgcn_mfma_f32_16x16x32_bf16(am[mt], bm, cc, 0, 0, 0);
        acc[mt][nt] = cc;
      }
    }
    __syncthreads();  // protect LDS before next chunk's DMA overwrite
  }

  // ---- store partial logits: C/D row(token)=quad*4+r, col(expert)=lane&15
#pragma unroll
  for (int mt = 0; mt < 2; ++mt)
#pragma unroll
    for (int nt = 0; nt < 4; ++nt)
#pragma unroll
      for (int r = 0; r < 4; ++r) {
        const int token = tok0 + wv * 32 + mt * 16 + quad * 4 + r;
        const int e = nt * 16 + col;
        part[((size_t)s * NTOK + token) * NEXP + e] = acc[mt][nt][r];
      }
}

// K2: reduce 8 K-slice partials + bias, butterfly top-2, normalized softmax.
__global__ __launch_bounds__(256, 8)
void router_reduce(const float* __restrict__ part,
                   const float* __restrict__ bias, float* __restrict__ out) {
  const int lane = threadIdx.x & 63;
  const int wv = threadIdx.x >> 6;
  const float bl = bias[lane];
  const int t0 = blockIdx.x * 8 + wv * 2;
#pragma unroll
  for (int tt = 0; tt < 2; ++tt) {
    const int t = t0 + tt;
    float p[NSLICE];
#pragma unroll
    for (int sl = 0; sl < NSLICE; ++sl)
      p[sl] = part[((size_t)sl * NTOK + t) * NEXP + lane];
    float v1 = bl;
#pragma unroll
    for (int sl = 0; sl < NSLICE; ++sl) v1 += p[sl];
    int i1 = lane;
    float v2 = -INFINITY;
    int i2 = NEXP;
#pragma unroll
    for (int off = 32; off > 0; off >>= 1) {
      float ov1 = __shfl_xor(v1, off, 64);
      int   oi1 = __shfl_xor(i1, off, 64);
      float ov2 = __shfl_xor(v2, off, 64);
      int   oi2 = __shfl_xor(i2, off, 64);
      bool afirst = (v1 > ov1) || (v1 == ov1 && i1 < oi1);
      float w1v = afirst ? v1 : ov1;  int w1i = afirst ? i1 : oi1;
      float c1v = afirst ? v2 : ov2;  int c1i = afirst ? i2 : oi2;
      float c2v = afirst ? ov1 : v1;  int c2i = afirst ? oi1 : i1;
      bool sfirst = (c1v > c2v) || (c1v == c2v && c1i < c2i);
      v1 = w1v; i1 = w1i;
      v2 = sfirst ? c1v : c2v;
      i2 = sfirst ? c1i : c2i;
    }
    if (lane == 0) {
      const float ex = expf(v2 - v1);
      const float den = 1.f + ex;
      *(float2*)(out + 2 * t) = make_float2(1.f / den, ex / den);
      *(float2*)(out + 2 * NTOK + 2 * t) = make_float2((float)i1, (float)i2);
    }
  }
}

// Fallback (ws too small): round-2-structure kernel, inline W split.
__global__ __launch_bounds__(512, 2)
void router_fb(const float* __restrict__ x, const float* __restrict__ W,
               const float* __restrict__ bias, float* __restrict__ out) {
  const int lane = threadIdx.x & 63;
  const int wv = threadIdx.x >> 6;
  const int col = lane & 15;
  const int quad = lane >> 4;
  const int tok0 = blockIdx.x * 32;
  const int k0 = wv * 256;

  __shared__ float part[8][32][68];

  f32x4 acc[2][4];
#pragma unroll
  for (int ms = 0; ms < 2; ++ms)
#pragma unroll
    for (int nt = 0; nt < 4; ++nt) acc[ms][nt] = (f32x4){0.f, 0.f, 0.f, 0.f};

  for (int ks = 0; ks < 8; ++ks) {
    const int k = k0 + ks * 32 + quad * 8;
    short8 ah[2], am2[2], al2[2];
#pragma unroll
    for (int ms = 0; ms < 2; ++ms) {
      const f32x4* ap = (const f32x4*)(x + (size_t)(tok0 + ms * 16 + col) * DM + k);
      f32x4 a0 = ap[0], a1 = ap[1];
      split8(a0, a1, ah[ms], am2[ms], al2[ms]);
    }
#pragma unroll
    for (int nt = 0; nt < 4; ++nt) {
      short8 bh, bm, bl;
      const f32x4* wp = (const f32x4*)(W + (size_t)(nt * 16 + col) * DM + k);
      f32x4 w0 = wp[0], w1 = wp[1];
      split8(w0, w1, bh, bm, bl);
#pragma unroll
      for (int ms = 0; ms < 2; ++ms) {
        f32x4 cc = acc[ms][nt];
        cc = __builtin_amdgcn_mfma_f32_16x16x32_bf16(ah[ms], bh, cc, 0, 0, 0);
        cc = __builtin_amdgcn_mfma_f32_16x16x32_bf16(ah[ms], bm, cc, 0, 0, 0);
        cc = __builtin_amdgcn_mfma_f32_16x16x32_bf16(am2[ms], bh, cc, 0, 0, 0);
        cc = __builtin_amdgcn_mfma_f32_16x16x32_bf16(ah[ms], bl, cc, 0, 0, 0);
        cc = __builtin_amdgcn_mfma_f32_16x16x32_bf16(al2[ms], bh, cc, 0, 0, 0);
        cc = __builtin_amdgcn_mfma_f32_16x16x32_bf16(am2[ms], bm, cc, 0, 0, 0);
        acc[ms][nt] = cc;
      }
    }
  }
#pragma unroll
  for (int ms = 0; ms < 2; ++ms)
#pragma unroll
    for (int nt = 0; nt < 4; ++nt)
#pragma unroll
      for (int r = 0; r < 4; ++r)
        part[wv][ms * 16 + quad * 4 + r][nt * 16 + col] = acc[ms][nt][r];
  __syncthreads();
  const float bl_ = bias[lane];
#pragma unroll
  for (int ti = 0; ti < 4; ++ti) {
    const int t = wv * 4 + ti;
    float v1 = bl_;
#pragma unroll
    for (int p = 0; p < 8; ++p) v1 += part[p][t][lane];
    int i1 = lane;
    float v2 = -INFINITY;
    int i2 = NEXP;
#pragma unroll
    for (int off = 32; off > 0; off >>= 1) {
      float ov1 = __shfl_xor(v1, off, 64);
      int   oi1 = __shfl_xor(i1, off, 64);
      float ov2 = __shfl_xor(v2, off, 64);
      int   oi2 = __shfl_xor(i2, off, 64);
      bool afirst = (v1 > ov1) || (v1 == ov1 && i1 < oi1);
      float w1v = afirst ? v1 : ov1;  int w1i = afirst ? i1 : oi1;
      float c1v = afirst ? v2 : ov2;  int c1i = afirst ? i2 : oi2;
      float c2v = afirst ? ov1 : v1;  int c2i = afirst ? oi1 : i1;
      bool sfirst = (c1v > c2v) || (c1v == c2v && c1i < c2i);
      v1 = w1v; i1 = w1i;
      v2 = sfirst ? c1v : c2v;
      i2 = sfirst ? c1i : c2i;
    }
    if (lane == 0) {
      const float ex = expf(v2 - v1);
      const float den = 1.f + ex;
      const int token = tok0 + t;
      *(float2*)(out + 2 * token) = make_float2(1.f / den, ex / den);
      *(float2*)(out + 2 * NTOK + 2 * token) =
          make_float2((float)i1, (float)i2);
    }
  }
}

extern "C" void kernel_launch(void* const* d_in, const int* in_sizes, int n_in,
                              void* d_out, int out_size, void* d_ws, size_t ws_size,
                              hipStream_t stream) {
  const float* x = (const float*)d_in[0];
  const float* W = (const float*)d_in[1];
  const float* b = (const float*)d_in[2];
  float* out = (float*)d_out;

  const size_t need = (size_t)WFRAG_BYTES + (size_t)PART_BYTES; // ~34.4 MB
  if (ws_size >= need) {
    unsigned short* wfrag = (unsigned short*)d_ws;
    float* part = (float*)((char*)d_ws + WFRAG_BYTES);
    hipLaunchKernelGGL(convw_kernel, dim3(64), dim3(256), 0, stream, W, wfrag);
    hipLaunchKernelGGL(router_gemm, dim3(NBLK1), dim3(256), 0, stream,
                       x, wfrag, part);
    hipLaunchKernelGGL(router_reduce, dim3(NTOK / 8), dim3(256), 0, stream,
                       part, b, out);
  } else {
    hipLaunchKernelGGL(router_fb, dim3(NTOK / 32), dim3(512), 0, stream,
                       x, W, b, out);
  }
}

// Round 5
// 207.725 us; speedup vs baseline: 1.1265x; 1.0459x over previous
//
#include <hip/hip_runtime.h>
#include <math.h>

#define DM 2048
#define NEXP 64
#define NTOK 16384
#define NSLICE 4
#define KSL (DM / NSLICE)     // 512 k per block (K-slice)
#define KC 32                 // k per chunk == one MFMA k-step
#define NCH (KSL / KC)        // 16 chunks per block
#define MB 64                 // tokens per block (4 waves x 1 M-tile x 16)
#define NBLK1 ((NTOK / MB) * NSLICE)  // 1024 blocks
#define NKG (DM / KC)                 // 64 global k-steps
#define WFRAG_BYTES (NKG * 12 * 1024) // [kg 64][limb*4+nt 12][64 lanes][16B]
#define PART_BYTES (NSLICE * NTOK * NEXP * 4)  // 16.8 MB

typedef __attribute__((ext_vector_type(8))) short short8;
typedef __attribute__((ext_vector_type(4))) float f32x4;

// Async global->LDS DMA, 16B/lane; dest = uniform base + lane*16. No dest
// VGPRs -> compiler cannot serialize; tracked by vmcnt.
__device__ __forceinline__ void async16(void* lds, const void* g) {
  __builtin_amdgcn_global_load_lds(
      (const __attribute__((address_space(1))) unsigned int*)g,
      (__attribute__((address_space(3))) unsigned int*)lds, 16, 0, 0);
}

// Fine-grained pipeline barriers (AITER-style: vmcnt never drains to 0 in
// steady state). Raw asm so the compiler's syncthreads lowering can't insert
// s_waitcnt vmcnt(0).
#define PIPE_BARRIER_KEEP5() \
  asm volatile("s_waitcnt vmcnt(5)\n\ts_barrier" ::: "memory")
#define PIPE_BARRIER_DRAIN() \
  asm volatile("s_waitcnt vmcnt(0)\n\ts_barrier" ::: "memory")
#define COMPUTE_DONE_BARRIER() \
  asm volatile("s_waitcnt lgkmcnt(0)\n\ts_barrier" ::: "memory")

// Truncating 3-limb bf16 split: f = h+m+l, residual ~2^-24 rel.
__device__ __forceinline__ void split3t(float f, unsigned short& h,
                                        unsigned short& m, unsigned short& l) {
  unsigned u = __float_as_uint(f);
  h = (unsigned short)(u >> 16);
  float f1 = f - __uint_as_float(u & 0xFFFF0000u);   // exact
  unsigned u1 = __float_as_uint(f1);
  m = (unsigned short)(u1 >> 16);
  float f2 = f1 - __uint_as_float(u1 & 0xFFFF0000u); // exact
  l = (unsigned short)(__float_as_uint(f2) >> 16);
}

__device__ __forceinline__ void split8(const f32x4& a0, const f32x4& a1,
                                       short8& h, short8& m, short8& l) {
  float v[8] = {a0[0], a0[1], a0[2], a0[3], a1[0], a1[1], a1[2], a1[3]};
#pragma unroll
  for (int j = 0; j < 8; ++j) {
    unsigned short hh, mm, ll;
    split3t(v[j], hh, mm, ll);
    h[j] = (short)hh; m[j] = (short)mm; l[j] = (short)ll;
  }
}

// Pre-split W into MFMA-B-fragment-ordered limb blocks:
// wfrag[((kg*12 + limb*4 + nt)*64 + lane)*8 + j] =
//   limb of W[nt*16 + (lane&15)][kg*32 + (lane>>4)*8 + j]
__global__ void convw_kernel(const float* __restrict__ W,
                             unsigned short* __restrict__ wfrag) {
  const int kg = blockIdx.x;
  const int lane = threadIdx.x & 63;
  const int nt = threadIdx.x >> 6;
  const int e = nt * 16 + (lane & 15);
  const int kpos = kg * 32 + (lane >> 4) * 8;
  const f32x4* wp = (const f32x4*)(W + (size_t)e * DM + kpos);
  f32x4 w0 = wp[0], w1 = wp[1];
  short8 h, m, l;
  split8(w0, w1, h, m, l);
  size_t base = ((size_t)(kg * 12 + nt) * 64 + lane) * 8;
  *(short8*)(wfrag + base) = h;
  *(short8*)(wfrag + base + (size_t)4 * 64 * 8) = m;
  *(short8*)(wfrag + base + (size_t)8 * 64 * 8) = l;
}

// K1: double-buffered DMA-pipelined bf16x3 MFMA GEMM, partials to global.
// Block: 4 waves x 16 tokens, K-slice 512 in 16 chunks of 32.
__global__ __launch_bounds__(256, 4)
void router_gemm(const float* __restrict__ x,
                 const unsigned short* __restrict__ wfrag,
                 float* __restrict__ part) {
  const int lane = threadIdx.x & 63;
  const int wv = threadIdx.x >> 6;
  const int col = lane & 15;
  const int quad = lane >> 4;
  const int tg = blockIdx.x >> 2;     // token group 0..255
  const int s = blockIdx.x & 3;       // K-slice 0..3
  const int tok0 = tg * MB;

  __shared__ __align__(16) float xs[2][MB][KC];              // 2 x 8 KB
  __shared__ __align__(16) unsigned short bs[2][12][64][8];  // 2 x 12 KB

  // Wave-invariant pieces of DMA addressing
  const int xrow_in = lane >> 3;                 // sub-row within 8-row strip
  const int xunit = (lane & 7) ^ (xrow_in & 7);  // XOR-swizzled 16B unit
  const float* xsrc0 =
      x + (size_t)(tok0 + wv * 16 + xrow_in) * DM + s * KSL + xunit * 4;
  const unsigned short* bsrc0 =
      wfrag + ((size_t)(s * NCH) * 12 + wv * 3) * 512 + (size_t)lane * 8;

  f32x4 acc[4];
#pragma unroll
  for (int nt = 0; nt < 4; ++nt) acc[nt] = (f32x4){0.f, 0.f, 0.f, 0.f};

  // ---- stage(c, buf): 5 DMA insts per wave (2 x-tile + 3 B-frag) ----
  auto stage = [&](int buf, int c) {
#pragma unroll
    for (int i = 0; i < 2; ++i)
      async16(&xs[buf][wv * 16 + i * 8][0], xsrc0 + i * 8 * DM + c * KC);
#pragma unroll
    for (int q = 0; q < 3; ++q)
      async16(&bs[buf][wv * 3 + q][0][0], bsrc0 + ((size_t)c * 12 + q) * 512);
  };

  stage(0, 0);  // prologue: 5 in flight

  for (int c = 0; c < NCH; ++c) {
    const int cur = c & 1;
    if (c + 1 < NCH) {
      stage(cur ^ 1, c + 1);     // 10 in flight
      PIPE_BARRIER_KEEP5();      // wait stage c only; c+1 stays in flight
    } else {
      PIPE_BARRIER_DRAIN();
    }

    // ---- A fragment: un-swizzled read + limb split (row&7 == col&7) ----
    const int row = wv * 16 + col;
    const int u0 = (quad * 2) ^ (col & 7);
    const int u1 = (quad * 2 + 1) ^ (col & 7);
    f32x4 a0 = *(const f32x4*)&xs[cur][row][u0 * 4];
    f32x4 a1 = *(const f32x4*)&xs[cur][row][u1 * 4];
    short8 ah, am, al;
    split8(a0, a1, ah, am, al);

    // ---- B fragments + 6-product MFMA ----
#pragma unroll
    for (int nt = 0; nt < 4; ++nt) {
      short8 bh = *(const short8*)&bs[cur][nt][lane][0];
      short8 bm = *(const short8*)&bs[cur][4 + nt][lane][0];
      short8 bl = *(const short8*)&bs[cur][8 + nt][lane][0];
      f32x4 cc = acc[nt];
      cc = __builtin_amdgcn_mfma_f32_16x16x32_bf16(ah, bh, cc, 0, 0, 0);
      cc = __builtin_amdgcn_mfma_f32_16x16x32_bf16(ah, bm, cc, 0, 0, 0);
      cc = __builtin_amdgcn_mfma_f32_16x16x32_bf16(am, bh, cc, 0, 0, 0);
      cc = __builtin_amdgcn_mfma_f32_16x16x32_bf16(ah, bl, cc, 0, 0, 0);
      cc = __builtin_amdgcn_mfma_f32_16x16x32_bf16(al, bh, cc, 0, 0, 0);
      cc = __builtin_amdgcn_mfma_f32_16x16x32_bf16(am, bm, cc, 0, 0, 0);
      acc[nt] = cc;
    }
    COMPUTE_DONE_BARRIER();  // all waves done reading buf[cur]; next iter
                             // may DMA into it
  }

  // ---- store partial logits: C/D row(token)=quad*4+r, col(expert)=lane&15
#pragma unroll
  for (int nt = 0; nt < 4; ++nt)
#pragma unroll
    for (int r = 0; r < 4; ++r) {
      const int token = tok0 + wv * 16 + quad * 4 + r;
      part[((size_t)s * NTOK + token) * NEXP + nt * 16 + col] = acc[nt][r];
    }
}

// K2: reduce 4 K-slice partials + bias, butterfly top-2, normalized softmax.
__global__ __launch_bounds__(256, 8)
void router_reduce(const float* __restrict__ part,
                   const float* __restrict__ bias, float* __restrict__ out) {
  const int lane = threadIdx.x & 63;
  const int wv = threadIdx.x >> 6;
  const float bl = bias[lane];
  const int t0 = blockIdx.x * 8 + wv * 2;
#pragma unroll
  for (int tt = 0; tt < 2; ++tt) {
    const int t = t0 + tt;
    float v1 = bl;
#pragma unroll
    for (int sl = 0; sl < NSLICE; ++sl)
      v1 += part[((size_t)sl * NTOK + t) * NEXP + lane];
    int i1 = lane;
    float v2 = -INFINITY;
    int i2 = NEXP;
#pragma unroll
    for (int off = 32; off > 0; off >>= 1) {
      float ov1 = __shfl_xor(v1, off, 64);
      int   oi1 = __shfl_xor(i1, off, 64);
      float ov2 = __shfl_xor(v2, off, 64);
      int   oi2 = __shfl_xor(i2, off, 64);
      bool afirst = (v1 > ov1) || (v1 == ov1 && i1 < oi1);
      float w1v = afirst ? v1 : ov1;  int w1i = afirst ? i1 : oi1;
      float c1v = afirst ? v2 : ov2;  int c1i = afirst ? i2 : oi2;
      float c2v = afirst ? ov1 : v1;  int c2i = afirst ? oi1 : i1;
      bool sfirst = (c1v > c2v) || (c1v == c2v && c1i < c2i);
      v1 = w1v; i1 = w1i;
      v2 = sfirst ? c1v : c2v;
      i2 = sfirst ? c1i : c2i;
    }
    if (lane == 0) {
      const float ex = expf(v2 - v1);
      const float den = 1.f + ex;
      *(float2*)(out + 2 * t) = make_float2(1.f / den, ex / den);
      *(float2*)(out + 2 * NTOK + 2 * t) = make_float2((float)i1, (float)i2);
    }
  }
}

// Fallback (ws too small): R4 verified single-kernel path, inline W split.
__global__ __launch_bounds__(512, 2)
void router_fb(const float* __restrict__ x, const float* __restrict__ W,
               const float* __restrict__ bias, float* __restrict__ out) {
  const int lane = threadIdx.x & 63;
  const int wv = threadIdx.x >> 6;
  const int col = lane & 15;
  const int quad = lane >> 4;
  const int tok0 = blockIdx.x * 32;
  const int k0 = wv * 256;

  __shared__ float part[8][32][68];

  f32x4 acc[2][4];
#pragma unroll
  for (int ms = 0; ms < 2; ++ms)
#pragma unroll
    for (int nt = 0; nt < 4; ++nt) acc[ms][nt] = (f32x4){0.f, 0.f, 0.f, 0.f};

  for (int ks = 0; ks < 8; ++ks) {
    const int k = k0 + ks * 32 + quad * 8;
    short8 ah[2], am2[2], al2[2];
#pragma unroll
    for (int ms = 0; ms < 2; ++ms) {
      const f32x4* ap = (const f32x4*)(x + (size_t)(tok0 + ms * 16 + col) * DM + k);
      f32x4 a0 = ap[0], a1 = ap[1];
      split8(a0, a1, ah[ms], am2[ms], al2[ms]);
    }
#pragma unroll
    for (int nt = 0; nt < 4; ++nt) {
      short8 bh, bm, bl;
      const f32x4* wp = (const f32x4*)(W + (size_t)(nt * 16 + col) * DM + k);
      f32x4 w0 = wp[0], w1 = wp[1];
      split8(w0, w1, bh, bm, bl);
#pragma unroll
      for (int ms = 0; ms < 2; ++ms) {
        f32x4 cc = acc[ms][nt];
        cc = __builtin_amdgcn_mfma_f32_16x16x32_bf16(ah[ms], bh, cc, 0, 0, 0);
        cc = __builtin_amdgcn_mfma_f32_16x16x32_bf16(ah[ms], bm, cc, 0, 0, 0);
        cc = __builtin_amdgcn_mfma_f32_16x16x32_bf16(am2[ms], bh, cc, 0, 0, 0);
        cc = __builtin_amdgcn_mfma_f32_16x16x32_bf16(ah[ms], bl, cc, 0, 0, 0);
        cc = __builtin_amdgcn_mfma_f32_16x16x32_bf16(al2[ms], bh, cc, 0, 0, 0);
        cc = __builtin_amdgcn_mfma_f32_16x16x32_bf16(am2[ms], bm, cc, 0, 0, 0);
        acc[ms][nt] = cc;
      }
    }
  }
#pragma unroll
  for (int ms = 0; ms < 2; ++ms)
#pragma unroll
    for (int nt = 0; nt < 4; ++nt)
#pragma unroll
      for (int r = 0; r < 4; ++r)
        part[wv][ms * 16 + quad * 4 + r][nt * 16 + col] = acc[ms][nt][r];
  __syncthreads();
  const float bl_ = bias[lane];
#pragma unroll
  for (int ti = 0; ti < 4; ++ti) {
    const int t = wv * 4 + ti;
    float v1 = bl_;
#pragma unroll
    for (int p = 0; p < 8; ++p) v1 += part[p][t][lane];
    int i1 = lane;
    float v2 = -INFINITY;
    int i2 = NEXP;
#pragma unroll
    for (int off = 32; off > 0; off >>= 1) {
      float ov1 = __shfl_xor(v1, off, 64);
      int   oi1 = __shfl_xor(i1, off, 64);
      float ov2 = __shfl_xor(v2, off, 64);
      int   oi2 = __shfl_xor(i2, off, 64);
      bool afirst = (v1 > ov1) || (v1 == ov1 && i1 < oi1);
      float w1v = afirst ? v1 : ov1;  int w1i = afirst ? i1 : oi1;
      float c1v = afirst ? v2 : ov2;  int c1i = afirst ? i2 : oi2;
      float c2v = afirst ? ov1 : v1;  int c2i = afirst ? oi1 : i1;
      bool sfirst = (c1v > c2v) || (c1v == c2v && c1i < c2i);
      v1 = w1v; i1 = w1i;
      v2 = sfirst ? c1v : c2v;
      i2 = sfirst ? c1i : c2i;
    }
    if (lane == 0) {
      const float ex = expf(v2 - v1);
      const float den = 1.f + ex;
      const int token = tok0 + t;
      *(float2*)(out + 2 * token) = make_float2(1.f / den, ex / den);
      *(float2*)(out + 2 * NTOK + 2 * token) =
          make_float2((float)i1, (float)i2);
    }
  }
}

extern "C" void kernel_launch(void* const* d_in, const int* in_sizes, int n_in,
                              void* d_out, int out_size, void* d_ws, size_t ws_size,
                              hipStream_t stream) {
  const float* x = (const float*)d_in[0];
  const float* W = (const float*)d_in[1];
  const float* b = (const float*)d_in[2];
  float* out = (float*)d_out;

  const size_t need = (size_t)WFRAG_BYTES + (size_t)PART_BYTES; // ~17.6 MB
  if (ws_size >= need) {
    unsigned short* wfrag = (unsigned short*)d_ws;
    float* part = (float*)((char*)d_ws + WFRAG_BYTES);
    hipLaunchKernelGGL(convw_kernel, dim3(NKG), dim3(256), 0, stream, W, wfrag);
    hipLaunchKernelGGL(router_gemm, dim3(NBLK1), dim3(256), 0, stream,
                       x, wfrag, part);
    hipLaunchKernelGGL(router_reduce, dim3(NTOK / 8), dim3(256), 0, stream,
                       part, b, out);
  } else {
    hipLaunchKernelGGL(router_fb, dim3(NTOK / 32), dim3(512), 0, stream,
                       x, W, b, out);
  }
}